// Round 1
// baseline (411.211 us; speedup 1.0000x reference)
//
#include <hip/hip_runtime.h>
#include <math.h>

// Problem dims (fixed)
namespace {
constexpr int Bb  = 4;
constexpr int Tt  = 2048;
constexpr int DM  = 768;
constexpr int Hh  = 4;
constexpr int Dd  = 64;
constexpr int DIM = 256;          // H*D
constexpr int BT  = Bb * Tt;      // 8192
constexpr int CH  = 64;           // chunk length
constexpr int NC  = Tt / CH;      // 32 chunks
}

__device__ __forceinline__ float elu1(float x) { return x > 0.f ? x + 1.f : expf(x); }

// ---------------------------------------------------------------------------
// K1: Q/K/V projections. out = act(x @ W). M=8192, K=768, N=256.
// blockIdx.z selects {Wq->Q (elu+1), Wk->K (elu+1), Wv->V (none)}.
// 64x64 tile, 16x16 threads, 4x4 per thread, Ktile=16.
// ---------------------------------------------------------------------------
__global__ __launch_bounds__(256) void k_qkv(
    const float* __restrict__ x, const float* __restrict__ Wq,
    const float* __restrict__ Wk, const float* __restrict__ Wv,
    float* __restrict__ Q, float* __restrict__ K, float* __restrict__ V) {
  __shared__ float As[16][68];
  __shared__ float Bs[16][68];
  const int z = blockIdx.z;
  const float* __restrict__ W = (z == 0) ? Wq : (z == 1) ? Wk : Wv;
  float* __restrict__ out = (z == 0) ? Q : (z == 1) ? K : V;
  const int tx = threadIdx.x, ty = threadIdx.y;
  const int tid = ty * 16 + tx;
  const int m0 = blockIdx.x * 64;
  const int n0 = blockIdx.y * 64;
  float acc[4][4] = {};
  for (int k0 = 0; k0 < DM; k0 += 16) {
#pragma unroll
    for (int l = 0; l < 4; ++l) {
      int idx = tid + l * 256;
      int kk = idx & 15, mm = idx >> 4;
      As[kk][mm] = x[(size_t)(m0 + mm) * DM + (k0 + kk)];
    }
#pragma unroll
    for (int l = 0; l < 4; ++l) {
      int idx = tid + l * 256;
      int nn = idx & 63, kk = idx >> 6;
      Bs[kk][nn] = W[(size_t)(k0 + kk) * DIM + (n0 + nn)];
    }
    __syncthreads();
#pragma unroll
    for (int kk = 0; kk < 16; ++kk) {
      float4 a4 = *(const float4*)&As[kk][ty * 4];
      float4 b4 = *(const float4*)&Bs[kk][tx * 4];
      float av[4] = {a4.x, a4.y, a4.z, a4.w};
      float bv[4] = {b4.x, b4.y, b4.z, b4.w};
#pragma unroll
      for (int i = 0; i < 4; ++i)
#pragma unroll
        for (int j = 0; j < 4; ++j) acc[i][j] += av[i] * bv[j];
    }
    __syncthreads();
  }
#pragma unroll
  for (int i = 0; i < 4; ++i)
#pragma unroll
    for (int j = 0; j < 4; ++j) {
      float v = acc[i][j];
      if (z < 2) v = elu1(v);
      out[(size_t)(m0 + ty * 4 + i) * DIM + (n0 + tx * 4 + j)] = v;
    }
}

// ---------------------------------------------------------------------------
// K2: per-chunk local sums. S_c[d][e] = sum_{t in chunk} K[t,d]*V[t,e];
//     z_c[d] = sum_t K[t,d].   One block per (c,h,b).
// ---------------------------------------------------------------------------
__global__ __launch_bounds__(256) void k_chunksum(
    const float* __restrict__ K, const float* __restrict__ V,
    float* __restrict__ Sc, float* __restrict__ zc) {
  __shared__ float Ks[CH][68];
  __shared__ float Vs[CH][68];
  const int c = blockIdx.x, h = blockIdx.y, b = blockIdx.z;
  const int tx = threadIdx.x, ty = threadIdx.y;
  const int tid = ty * 16 + tx;
  const int t0 = c * CH;
#pragma unroll
  for (int l = 0; l < 16; ++l) {
    int idx = tid + l * 256;
    int d = idx & 63, t = idx >> 6;
    size_t row = (size_t)(b * Tt + t0 + t) * DIM + h * Dd;
    Ks[t][d] = K[row + d];
    Vs[t][d] = V[row + d];
  }
  __syncthreads();
  float acc[4][4] = {};
  for (int t = 0; t < CH; ++t) {
    float4 k4 = *(const float4*)&Ks[t][ty * 4];
    float4 v4 = *(const float4*)&Vs[t][tx * 4];
    float kv[4] = {k4.x, k4.y, k4.z, k4.w};
    float vv[4] = {v4.x, v4.y, v4.z, v4.w};
#pragma unroll
    for (int i = 0; i < 4; ++i)
#pragma unroll
      for (int j = 0; j < 4; ++j) acc[i][j] += kv[i] * vv[j];
  }
  const size_t base = ((size_t)(b * Hh + h) * NC + c) * (Dd * Dd);
#pragma unroll
  for (int i = 0; i < 4; ++i) {
    float4 s4 = make_float4(acc[i][0], acc[i][1], acc[i][2], acc[i][3]);
    *(float4*)&Sc[base + (size_t)(ty * 4 + i) * Dd + tx * 4] = s4;
  }
  if (tid < Dd) {
    float s = 0.f;
    for (int t = 0; t < CH; ++t) s += Ks[t][tid];
    zc[((size_t)(b * Hh + h) * NC + c) * Dd + tid] = s;
  }
}

// ---------------------------------------------------------------------------
// K3: exclusive prefix scan over chunks (in-place). One block per (b,h).
// ---------------------------------------------------------------------------
__global__ __launch_bounds__(256) void k_scan(float* __restrict__ Sc,
                                              float* __restrict__ zc) {
  const int bh = blockIdx.x;
  const int tid = threadIdx.x;
  float run[16];
#pragma unroll
  for (int l = 0; l < 16; ++l) run[l] = 0.f;
  for (int c = 0; c < NC; ++c) {
    size_t base = ((size_t)bh * NC + c) * (Dd * Dd);
#pragma unroll
    for (int l = 0; l < 16; ++l) {
      size_t o = base + tid + l * 256;
      float cur = Sc[o];
      Sc[o] = run[l];
      run[l] += cur;
    }
  }
  if (tid < Dd) {
    float rz = 0.f;
    for (int c = 0; c < NC; ++c) {
      size_t o = ((size_t)bh * NC + c) * Dd + tid;
      float cur = zc[o];
      zc[o] = rz;
      rz += cur;
    }
  }
}

// ---------------------------------------------------------------------------
// K4: per-chunk output.
//   A = tril(Q K^T) (diag incl); O = A@V + Q@S_prev; den = rowsum(A)+Q.z_prev
// One block per (c,h,b). LDS ~70 KB -> 2 blocks/CU.
// ---------------------------------------------------------------------------
__global__ __launch_bounds__(256) void k_out(
    const float* __restrict__ Q, const float* __restrict__ K,
    const float* __restrict__ V, const float* __restrict__ Sc,
    const float* __restrict__ zc, float* __restrict__ O) {
  __shared__ float Qs[CH][68];
  __shared__ float KVs[CH * 68];  // K transposed (pad 65) then V row-major (pad 68)
  __shared__ float As[CH][68];
  __shared__ float Ss[Dd][68];
  __shared__ float zs[Dd];
  __shared__ float dens[CH];
  const int c = blockIdx.x, h = blockIdx.y, b = blockIdx.z;
  const int tx = threadIdx.x, ty = threadIdx.y;
  const int tid = ty * 16 + tx;
  const int t0 = c * CH;

  // load Q chunk [t][d], K chunk transposed [d][t] (pad 65 -> conflict-free)
#pragma unroll
  for (int l = 0; l < 16; ++l) {
    int idx = tid + l * 256;
    int d = idx & 63, t = idx >> 6;
    size_t row = (size_t)(b * Tt + t0 + t) * DIM + h * Dd;
    Qs[t][d] = Q[row + d];
    KVs[d * 65 + t] = K[row + d];
  }
  __syncthreads();

  // A[i][j] = sum_d Q[i][d]*K[j][d], masked j<=i
  float acc[4][4] = {};
  for (int d0 = 0; d0 < Dd; d0 += 4) {
    float4 q4[4];
#pragma unroll
    for (int i = 0; i < 4; ++i) q4[i] = *(const float4*)&Qs[ty * 4 + i][d0];
#pragma unroll
    for (int dd = 0; dd < 4; ++dd) {
      int d = d0 + dd;
      float kv[4];
#pragma unroll
      for (int j = 0; j < 4; ++j) kv[j] = KVs[d * 65 + tx * 4 + j];
#pragma unroll
      for (int i = 0; i < 4; ++i) {
        float qv = ((const float*)&q4[i])[dd];
#pragma unroll
        for (int j = 0; j < 4; ++j) acc[i][j] += qv * kv[j];
      }
    }
  }
#pragma unroll
  for (int i = 0; i < 4; ++i)
#pragma unroll
    for (int j = 0; j < 4; ++j) {
      int ti = ty * 4 + i, sj = tx * 4 + j;
      As[ti][sj] = (sj <= ti) ? acc[i][j] : 0.f;
    }
  __syncthreads();

  // reload V into KVs (row-major pad 68); load S_prev, z_prev
#pragma unroll
  for (int l = 0; l < 16; ++l) {
    int idx = tid + l * 256;
    int d = idx & 63, t = idx >> 6;
    size_t row = (size_t)(b * Tt + t0 + t) * DIM + h * Dd;
    KVs[t * 68 + d] = V[row + d];
  }
  const size_t sbase = ((size_t)(b * Hh + h) * NC + c) * (Dd * Dd);
#pragma unroll
  for (int l = 0; l < 16; ++l) {
    int idx = tid + l * 256;
    int e = idx & 63, dd = idx >> 6;
    Ss[dd][e] = Sc[sbase + idx];
  }
  if (tid < Dd) zs[tid] = zc[((size_t)(b * Hh + h) * NC + c) * Dd + tid];
  __syncthreads();

  // den per row (64 threads) + output accumulation (all threads)
  if (tid < CH) {
    int i = tid;
    float rs = 0.f;
    for (int j = 0; j < CH; ++j) rs += As[i][j];
    float qz = 0.f;
    for (int d = 0; d < Dd; ++d) qz += Qs[i][d] * zs[d];
    dens[i] = fmaxf(rs + qz, 1e-6f);
  }
  float oacc[4][4] = {};
  for (int j = 0; j < CH; ++j) {
    float4 v4 = *(const float4*)&KVs[j * 68 + tx * 4];
    float vv[4] = {v4.x, v4.y, v4.z, v4.w};
    float av[4];
#pragma unroll
    for (int i = 0; i < 4; ++i) av[i] = As[ty * 4 + i][j];
#pragma unroll
    for (int i = 0; i < 4; ++i)
#pragma unroll
      for (int jj = 0; jj < 4; ++jj) oacc[i][jj] += av[i] * vv[jj];
  }
  for (int d = 0; d < Dd; ++d) {
    float4 s4 = *(const float4*)&Ss[d][tx * 4];
    float sv[4] = {s4.x, s4.y, s4.z, s4.w};
    float qv[4];
#pragma unroll
    for (int i = 0; i < 4; ++i) qv[i] = Qs[ty * 4 + i][d];
#pragma unroll
    for (int i = 0; i < 4; ++i)
#pragma unroll
      for (int jj = 0; jj < 4; ++jj) oacc[i][jj] += qv[i] * sv[jj];
  }
  __syncthreads();
#pragma unroll
  for (int i = 0; i < 4; ++i) {
    float inv = 1.f / dens[ty * 4 + i];
#pragma unroll
    for (int jj = 0; jj < 4; ++jj) {
      O[(size_t)(b * Tt + t0 + ty * 4 + i) * DIM + h * Dd + tx * 4 + jj] =
          oacc[i][jj] * inv;
    }
  }
}

// ---------------------------------------------------------------------------
// K5: fused final: out = (O @ Wo) * sigmoid(x @ Wg). M=8192, N=768.
// ---------------------------------------------------------------------------
__global__ __launch_bounds__(256) void k_final(
    const float* __restrict__ O, const float* __restrict__ Wo,
    const float* __restrict__ x, const float* __restrict__ Wg,
    float* __restrict__ out) {
  __shared__ float As[16][68];
  __shared__ float Bs[16][68];
  const int tx = threadIdx.x, ty = threadIdx.y;
  const int tid = ty * 16 + tx;
  const int m0 = blockIdx.x * 64;
  const int n0 = blockIdx.y * 64;
  float acc1[4][4] = {}, acc2[4][4] = {};
  // pass 1: O @ Wo  (K = 256)
  for (int k0 = 0; k0 < DIM; k0 += 16) {
#pragma unroll
    for (int l = 0; l < 4; ++l) {
      int idx = tid + l * 256;
      int kk = idx & 15, mm = idx >> 4;
      As[kk][mm] = O[(size_t)(m0 + mm) * DIM + (k0 + kk)];
    }
#pragma unroll
    for (int l = 0; l < 4; ++l) {
      int idx = tid + l * 256;
      int nn = idx & 63, kk = idx >> 6;
      Bs[kk][nn] = Wo[(size_t)(k0 + kk) * DM + (n0 + nn)];
    }
    __syncthreads();
#pragma unroll
    for (int kk = 0; kk < 16; ++kk) {
      float4 a4 = *(const float4*)&As[kk][ty * 4];
      float4 b4 = *(const float4*)&Bs[kk][tx * 4];
      float av[4] = {a4.x, a4.y, a4.z, a4.w};
      float bv[4] = {b4.x, b4.y, b4.z, b4.w};
#pragma unroll
      for (int i = 0; i < 4; ++i)
#pragma unroll
        for (int j = 0; j < 4; ++j) acc1[i][j] += av[i] * bv[j];
    }
    __syncthreads();
  }
  // pass 2: x @ Wg  (K = 768)
  for (int k0 = 0; k0 < DM; k0 += 16) {
#pragma unroll
    for (int l = 0; l < 4; ++l) {
      int idx = tid + l * 256;
      int kk = idx & 15, mm = idx >> 4;
      As[kk][mm] = x[(size_t)(m0 + mm) * DM + (k0 + kk)];
    }
#pragma unroll
    for (int l = 0; l < 4; ++l) {
      int idx = tid + l * 256;
      int nn = idx & 63, kk = idx >> 6;
      Bs[kk][nn] = Wg[(size_t)(k0 + kk) * DM + (n0 + nn)];
    }
    __syncthreads();
#pragma unroll
    for (int kk = 0; kk < 16; ++kk) {
      float4 a4 = *(const float4*)&As[kk][ty * 4];
      float4 b4 = *(const float4*)&Bs[kk][tx * 4];
      float av[4] = {a4.x, a4.y, a4.z, a4.w};
      float bv[4] = {b4.x, b4.y, b4.z, b4.w};
#pragma unroll
      for (int i = 0; i < 4; ++i)
#pragma unroll
        for (int j = 0; j < 4; ++j) acc2[i][j] += av[i] * bv[j];
    }
    __syncthreads();
  }
#pragma unroll
  for (int i = 0; i < 4; ++i)
#pragma unroll
    for (int j = 0; j < 4; ++j) {
      float g = 1.f / (1.f + expf(-acc2[i][j]));
      out[(size_t)(m0 + ty * 4 + i) * DM + (n0 + tx * 4 + j)] = acc1[i][j] * g;
    }
}

// ---------------------------------------------------------------------------
extern "C" void kernel_launch(void* const* d_in, const int* in_sizes, int n_in,
                              void* d_out, int out_size, void* d_ws,
                              size_t ws_size, hipStream_t stream) {
  const float* x  = (const float*)d_in[0];
  const float* Wq = (const float*)d_in[1];
  const float* Wk = (const float*)d_in[2];
  const float* Wv = (const float*)d_in[3];
  const float* Wo = (const float*)d_in[4];
  const float* Wg = (const float*)d_in[5];
  float* out = (float*)d_out;

  float* ws = (float*)d_ws;
  float* Q  = ws;
  float* Kf = Q + (size_t)BT * DIM;
  float* Vf = Kf + (size_t)BT * DIM;
  float* Of = Vf + (size_t)BT * DIM;
  float* Sc = Of + (size_t)BT * DIM;
  float* zc = Sc + (size_t)Bb * Hh * NC * Dd * Dd;
  // total ws use: ~10.5M floats = 42 MB

  dim3 blk(16, 16);
  k_qkv<<<dim3(BT / 64, DIM / 64, 3), blk, 0, stream>>>(x, Wq, Wk, Wv, Q, Kf, Vf);
  k_chunksum<<<dim3(NC, Hh, Bb), blk, 0, stream>>>(Kf, Vf, Sc, zc);
  k_scan<<<dim3(Bb * Hh), dim3(256), 0, stream>>>(Sc, zc);
  k_out<<<dim3(NC, Hh, Bb), blk, 0, stream>>>(Q, Kf, Vf, Sc, zc, Of);
  k_final<<<dim3(BT / 64, DM / 64), blk, 0, stream>>>(Of, Wo, x, Wg, out);
}

// Round 2
// 111.545 us; speedup vs baseline: 3.6865x; 3.6865x over previous
//
#include <hip/hip_runtime.h>
#include <math.h>

typedef __attribute__((ext_vector_type(8))) short bf16x8;
typedef __attribute__((ext_vector_type(4))) float f32x4;

namespace {
constexpr int Bb  = 4;
constexpr int Tt  = 2048;
constexpr int DM  = 768;
constexpr int Hh  = 4;
constexpr int Dd  = 64;
constexpr int DIM = 256;          // H*D
constexpr int BT  = Bb * Tt;      // 8192
constexpr int CH  = 64;           // chunk length
constexpr int NC  = Tt / CH;      // 32 chunks
}

__device__ __forceinline__ float elu1(float x) { return x > 0.f ? x + 1.f : expf(x); }

// fp32 -> bf16, round-to-nearest-even
__device__ __forceinline__ unsigned short f2bf(float f) {
  unsigned int x = __float_as_uint(f);
  unsigned int r = (x + 0x7fffu + ((x >> 16) & 1u)) >> 16;
  return (unsigned short)r;
}

__device__ __forceinline__ void gload16(const void* g, void* l) {
  __builtin_amdgcn_global_load_lds(
      (const __attribute__((address_space(1))) void*)g,
      (__attribute__((address_space(3))) void*)l, 16, 0, 0);
}

// stage a 128x64 bf16 tile (row-major, ld elements per source row) into lds
// (linear [128][64] shorts). 256 threads, 4 calls each, 16B per lane.
__device__ __forceinline__ void stage_tile(const short* __restrict__ gbase,
                                           size_t ld, int k0,
                                           short* lds, int w, int l) {
#pragma unroll
  for (int i = 0; i < 4; ++i) {
    int seg = w * 4 + i;
    int row = seg * 8 + (l >> 3);
    int kk  = (l & 7) * 8;
    gload16(gbase + (size_t)row * ld + k0 + kk, (char*)lds + seg * 1024);
  }
}

// ---------------------------------------------------------------------------
// cast fp32 -> bf16, 8 elements/thread
// ---------------------------------------------------------------------------
__global__ __launch_bounds__(256) void k_cast(const float* __restrict__ in,
                                              unsigned short* __restrict__ out,
                                              int n8) {
  int i = blockIdx.x * 256 + threadIdx.x;
  if (i >= n8) return;
  const float4* p = (const float4*)(in + (size_t)i * 8);
  float4 a = p[0], b = p[1];
  union { unsigned short u[8]; uint4 v; } r;
  r.u[0] = f2bf(a.x); r.u[1] = f2bf(a.y); r.u[2] = f2bf(a.z); r.u[3] = f2bf(a.w);
  r.u[4] = f2bf(b.x); r.u[5] = f2bf(b.y); r.u[6] = f2bf(b.z); r.u[7] = f2bf(b.w);
  *(uint4*)(out + (size_t)i * 8) = r.v;
}

// ---------------------------------------------------------------------------
// transpose + cast: in fp32 [K][N] row-major -> out bf16 rows [n_off+n][K]
// ---------------------------------------------------------------------------
__global__ __launch_bounds__(256) void k_convT(const float* __restrict__ in,
                                               unsigned short* __restrict__ out,
                                               int K, int N, int n_off, int ldo) {
  __shared__ float t[32][33];
  const int k0 = blockIdx.x * 32, n0 = blockIdx.y * 32;
  const int tx = threadIdx.x, ty = threadIdx.y;
  for (int i = ty; i < 32; i += 8)
    t[i][tx] = in[(size_t)(k0 + i) * N + n0 + tx];
  __syncthreads();
  for (int i = ty; i < 32; i += 8)
    out[(size_t)(n_off + n0 + i) * ldo + k0 + tx] = f2bf(t[tx][i]);
}

// ---------------------------------------------------------------------------
// MFMA GEMM: QKV = act(x @ [Wq|Wk|Wv]).  M=8192, K=768, N=768 (B^T input).
// 128x128 tile, 4 waves (2x2), each wave 64x64 = 4x4 fragments of 16x16x32.
// Epilogue: cols<512 -> elu+1; scatter to Q/K/V fp32 [8192][256].
// ---------------------------------------------------------------------------
__global__ __launch_bounds__(256) void k_gemm_qkv(
    const unsigned short* __restrict__ xb, const unsigned short* __restrict__ Wt,
    float* __restrict__ Q, float* __restrict__ K, float* __restrict__ V) {
  __shared__ short As[128 * 64];
  __shared__ short Bs[128 * 64];
  const int tid = threadIdx.x;
  const int w = tid >> 6, l = tid & 63;
  const int lr = l & 15, lg = l >> 4;
  const int wr = w >> 1, wc = w & 1;
  const int m0 = blockIdx.x * 128, n0 = blockIdx.y * 128;

  f32x4 acc[4][4];
#pragma unroll
  for (int i = 0; i < 4; ++i)
#pragma unroll
    for (int j = 0; j < 4; ++j) acc[i][j] = (f32x4){0.f, 0.f, 0.f, 0.f};

  for (int k0 = 0; k0 < DM; k0 += 64) {
    stage_tile((const short*)xb + (size_t)m0 * DM, DM, k0, As, w, l);
    stage_tile((const short*)Wt + (size_t)n0 * DM, DM, k0, Bs, w, l);
    __syncthreads();
#pragma unroll
    for (int ks = 0; ks < 2; ++ks) {
      bf16x8 af[4], bf[4];
#pragma unroll
      for (int mi = 0; mi < 4; ++mi)
        af[mi] = *(const bf16x8*)&As[(wr * 64 + mi * 16 + lr) * 64 + ks * 32 + lg * 8];
#pragma unroll
      for (int ni = 0; ni < 4; ++ni)
        bf[ni] = *(const bf16x8*)&Bs[(wc * 64 + ni * 16 + lr) * 64 + ks * 32 + lg * 8];
#pragma unroll
      for (int mi = 0; mi < 4; ++mi)
#pragma unroll
        for (int ni = 0; ni < 4; ++ni)
          acc[mi][ni] = __builtin_amdgcn_mfma_f32_16x16x32_bf16(
              af[mi], bf[ni], acc[mi][ni], 0, 0, 0);
    }
    __syncthreads();
  }

#pragma unroll
  for (int mi = 0; mi < 4; ++mi)
#pragma unroll
    for (int ni = 0; ni < 4; ++ni) {
      int col0 = n0 + wc * 64 + ni * 16;     // uniform across lanes
      float* dst = (col0 < 256) ? Q : (col0 < 512) ? K : V;
      bool act = col0 < 512;
      int c = (col0 & 255) + lr;
#pragma unroll
      for (int r = 0; r < 4; ++r) {
        int row = m0 + wr * 64 + mi * 16 + lg * 4 + r;
        float v = acc[mi][ni][r];
        if (act) v = elu1(v);
        dst[(size_t)row * DIM + c] = v;
      }
    }
}

// ---------------------------------------------------------------------------
// K2: per-chunk local sums (fp32 vector).
// ---------------------------------------------------------------------------
__global__ __launch_bounds__(256) void k_chunksum(
    const float* __restrict__ K, const float* __restrict__ V,
    float* __restrict__ Sc, float* __restrict__ zc) {
  __shared__ float Ks[CH][68];
  __shared__ float Vs[CH][68];
  const int c = blockIdx.x, h = blockIdx.y, b = blockIdx.z;
  const int tx = threadIdx.x, ty = threadIdx.y;
  const int tid = ty * 16 + tx;
  const int t0 = c * CH;
#pragma unroll
  for (int l = 0; l < 16; ++l) {
    int idx = tid + l * 256;
    int d = idx & 63, t = idx >> 6;
    size_t row = (size_t)(b * Tt + t0 + t) * DIM + h * Dd;
    Ks[t][d] = K[row + d];
    Vs[t][d] = V[row + d];
  }
  __syncthreads();
  float acc[4][4] = {};
  for (int t = 0; t < CH; ++t) {
    float4 k4 = *(const float4*)&Ks[t][ty * 4];
    float4 v4 = *(const float4*)&Vs[t][tx * 4];
    float kv[4] = {k4.x, k4.y, k4.z, k4.w};
    float vv[4] = {v4.x, v4.y, v4.z, v4.w};
#pragma unroll
    for (int i = 0; i < 4; ++i)
#pragma unroll
      for (int j = 0; j < 4; ++j) acc[i][j] += kv[i] * vv[j];
  }
  const size_t base = ((size_t)(b * Hh + h) * NC + c) * (Dd * Dd);
#pragma unroll
  for (int i = 0; i < 4; ++i) {
    float4 s4 = make_float4(acc[i][0], acc[i][1], acc[i][2], acc[i][3]);
    *(float4*)&Sc[base + (size_t)(ty * 4 + i) * Dd + tx * 4] = s4;
  }
  if (tid < Dd) {
    float s = 0.f;
    for (int t = 0; t < CH; ++t) s += Ks[t][tid];
    zc[((size_t)(b * Hh + h) * NC + c) * Dd + tid] = s;
  }
}

// ---------------------------------------------------------------------------
// K3: exclusive prefix scan over chunks. grid (16 bh, 16 slices) x 256.
// Each thread owns one of the 4096 S elements (or one of 64 z elements).
// ---------------------------------------------------------------------------
__global__ __launch_bounds__(256) void k_scan(float* __restrict__ Sc,
                                              float* __restrict__ zc) {
  const int bh = blockIdx.x;
  const int o = blockIdx.y * 256 + threadIdx.x;
  const size_t base = (size_t)bh * NC * (Dd * Dd) + o;
  float v[NC];
#pragma unroll
  for (int c = 0; c < NC; ++c) v[c] = Sc[base + (size_t)c * (Dd * Dd)];
  float run = 0.f;
#pragma unroll
  for (int c = 0; c < NC; ++c) {
    Sc[base + (size_t)c * (Dd * Dd)] = run;
    run += v[c];
  }
  if (blockIdx.y == 0 && threadIdx.x < Dd) {
    float rz = 0.f;
    for (int c = 0; c < NC; ++c) {
      size_t oz = ((size_t)bh * NC + c) * Dd + threadIdx.x;
      float cur = zc[oz];
      zc[oz] = rz;
      rz += cur;
    }
  }
}

// ---------------------------------------------------------------------------
// K4: per-chunk output (fp32 vector). Writes O as bf16.
// ---------------------------------------------------------------------------
__global__ __launch_bounds__(256) void k_out(
    const float* __restrict__ Q, const float* __restrict__ K,
    const float* __restrict__ V, const float* __restrict__ Sc,
    const float* __restrict__ zc, unsigned short* __restrict__ O) {
  __shared__ float Qs[CH][68];
  __shared__ float KVs[CH * 68];
  __shared__ float As[CH][68];
  __shared__ float Ss[Dd][68];
  __shared__ float zs[Dd];
  __shared__ float dens[CH];
  const int c = blockIdx.x, h = blockIdx.y, b = blockIdx.z;
  const int tx = threadIdx.x, ty = threadIdx.y;
  const int tid = ty * 16 + tx;
  const int t0 = c * CH;

#pragma unroll
  for (int l = 0; l < 16; ++l) {
    int idx = tid + l * 256;
    int d = idx & 63, t = idx >> 6;
    size_t row = (size_t)(b * Tt + t0 + t) * DIM + h * Dd;
    Qs[t][d] = Q[row + d];
    KVs[d * 65 + t] = K[row + d];
  }
  __syncthreads();

  float acc[4][4] = {};
  for (int d0 = 0; d0 < Dd; d0 += 4) {
    float4 q4[4];
#pragma unroll
    for (int i = 0; i < 4; ++i) q4[i] = *(const float4*)&Qs[ty * 4 + i][d0];
#pragma unroll
    for (int dd = 0; dd < 4; ++dd) {
      int d = d0 + dd;
      float kv[4];
#pragma unroll
      for (int j = 0; j < 4; ++j) kv[j] = KVs[d * 65 + tx * 4 + j];
#pragma unroll
      for (int i = 0; i < 4; ++i) {
        float qv = ((const float*)&q4[i])[dd];
#pragma unroll
        for (int j = 0; j < 4; ++j) acc[i][j] += qv * kv[j];
      }
    }
  }
#pragma unroll
  for (int i = 0; i < 4; ++i)
#pragma unroll
    for (int j = 0; j < 4; ++j) {
      int ti = ty * 4 + i, sj = tx * 4 + j;
      As[ti][sj] = (sj <= ti) ? acc[i][j] : 0.f;
    }
  __syncthreads();

#pragma unroll
  for (int l = 0; l < 16; ++l) {
    int idx = tid + l * 256;
    int d = idx & 63, t = idx >> 6;
    size_t row = (size_t)(b * Tt + t0 + t) * DIM + h * Dd;
    KVs[t * 68 + d] = V[row + d];
  }
  const size_t sbase = ((size_t)(b * Hh + h) * NC + c) * (Dd * Dd);
#pragma unroll
  for (int l = 0; l < 16; ++l) {
    int idx = tid + l * 256;
    int e = idx & 63, dd = idx >> 6;
    Ss[dd][e] = Sc[sbase + idx];
  }
  if (tid < Dd) zs[tid] = zc[((size_t)(b * Hh + h) * NC + c) * Dd + tid];
  __syncthreads();

  if (tid < CH) {
    int i = tid;
    float rs = 0.f;
    for (int j = 0; j < CH; ++j) rs += As[i][j];
    float qz = 0.f;
    for (int d = 0; d < Dd; ++d) qz += Qs[i][d] * zs[d];
    dens[i] = fmaxf(rs + qz, 1e-6f);
  }
  float oacc[4][4] = {};
  for (int j = 0; j < CH; ++j) {
    float4 v4 = *(const float4*)&KVs[j * 68 + tx * 4];
    float vv[4] = {v4.x, v4.y, v4.z, v4.w};
    float av[4];
#pragma unroll
    for (int i = 0; i < 4; ++i) av[i] = As[ty * 4 + i][j];
#pragma unroll
    for (int i = 0; i < 4; ++i)
#pragma unroll
      for (int jj = 0; jj < 4; ++jj) oacc[i][jj] += av[i] * vv[jj];
  }
  for (int d = 0; d < Dd; ++d) {
    float4 s4 = *(const float4*)&Ss[d][tx * 4];
    float sv[4] = {s4.x, s4.y, s4.z, s4.w};
    float qv[4];
#pragma unroll
    for (int i = 0; i < 4; ++i) qv[i] = Qs[ty * 4 + i][d];
#pragma unroll
    for (int i = 0; i < 4; ++i)
#pragma unroll
      for (int jj = 0; jj < 4; ++jj) oacc[i][jj] += qv[i] * sv[jj];
  }
  __syncthreads();
#pragma unroll
  for (int i = 0; i < 4; ++i) {
    float inv = 1.f / dens[ty * 4 + i];
#pragma unroll
    for (int jj = 0; jj < 4; ++jj) {
      O[(size_t)(b * Tt + t0 + ty * 4 + i) * DIM + h * Dd + tx * 4 + jj] =
          f2bf(oacc[i][jj] * inv);
    }
  }
}

// ---------------------------------------------------------------------------
// MFMA fused final: out = (O @ Wo) * sigmoid(x @ Wg). M=8192, N=768.
// Pass 1: acc2 = x@Wg (K=768); pass 2: acc1 = O@Wo (K=256).
// ---------------------------------------------------------------------------
__global__ __launch_bounds__(256) void k_gemm_final(
    const unsigned short* __restrict__ Ob, const unsigned short* __restrict__ WoT,
    const unsigned short* __restrict__ xb, const unsigned short* __restrict__ WgT,
    float* __restrict__ out) {
  __shared__ short As[128 * 64];
  __shared__ short Bs[128 * 64];
  const int tid = threadIdx.x;
  const int w = tid >> 6, l = tid & 63;
  const int lr = l & 15, lg = l >> 4;
  const int wr = w >> 1, wc = w & 1;
  const int m0 = blockIdx.x * 128, n0 = blockIdx.y * 128;

  f32x4 acc1[4][4], acc2[4][4];
#pragma unroll
  for (int i = 0; i < 4; ++i)
#pragma unroll
    for (int j = 0; j < 4; ++j) {
      acc1[i][j] = (f32x4){0.f, 0.f, 0.f, 0.f};
      acc2[i][j] = (f32x4){0.f, 0.f, 0.f, 0.f};
    }

  // pass 1: gate logits = x @ Wg  (K = 768)
  for (int k0 = 0; k0 < DM; k0 += 64) {
    stage_tile((const short*)xb + (size_t)m0 * DM, DM, k0, As, w, l);
    stage_tile((const short*)WgT + (size_t)n0 * DM, DM, k0, Bs, w, l);
    __syncthreads();
#pragma unroll
    for (int ks = 0; ks < 2; ++ks) {
      bf16x8 af[4], bf[4];
#pragma unroll
      for (int mi = 0; mi < 4; ++mi)
        af[mi] = *(const bf16x8*)&As[(wr * 64 + mi * 16 + lr) * 64 + ks * 32 + lg * 8];
#pragma unroll
      for (int ni = 0; ni < 4; ++ni)
        bf[ni] = *(const bf16x8*)&Bs[(wc * 64 + ni * 16 + lr) * 64 + ks * 32 + lg * 8];
#pragma unroll
      for (int mi = 0; mi < 4; ++mi)
#pragma unroll
        for (int ni = 0; ni < 4; ++ni)
          acc2[mi][ni] = __builtin_amdgcn_mfma_f32_16x16x32_bf16(
              af[mi], bf[ni], acc2[mi][ni], 0, 0, 0);
    }
    __syncthreads();
  }

  // pass 2: O @ Wo  (K = 256)
  for (int k0 = 0; k0 < DIM; k0 += 64) {
    stage_tile((const short*)Ob + (size_t)m0 * DIM, DIM, k0, As, w, l);
    stage_tile((const short*)WoT + (size_t)n0 * DIM, DIM, k0, Bs, w, l);
    __syncthreads();
#pragma unroll
    for (int ks = 0; ks < 2; ++ks) {
      bf16x8 af[4], bf[4];
#pragma unroll
      for (int mi = 0; mi < 4; ++mi)
        af[mi] = *(const bf16x8*)&As[(wr * 64 + mi * 16 + lr) * 64 + ks * 32 + lg * 8];
#pragma unroll
      for (int ni = 0; ni < 4; ++ni)
        bf[ni] = *(const bf16x8*)&Bs[(wc * 64 + ni * 16 + lr) * 64 + ks * 32 + lg * 8];
#pragma unroll
      for (int mi = 0; mi < 4; ++mi)
#pragma unroll
        for (int ni = 0; ni < 4; ++ni)
          acc1[mi][ni] = __builtin_amdgcn_mfma_f32_16x16x32_bf16(
              af[mi], bf[ni], acc1[mi][ni], 0, 0, 0);
    }
    __syncthreads();
  }

#pragma unroll
  for (int mi = 0; mi < 4; ++mi)
#pragma unroll
    for (int ni = 0; ni < 4; ++ni) {
      int col = n0 + wc * 64 + ni * 16 + lr;
#pragma unroll
      for (int r = 0; r < 4; ++r) {
        int row = m0 + wr * 64 + mi * 16 + lg * 4 + r;
        float g = 1.f / (1.f + expf(-acc2[mi][ni][r]));
        out[(size_t)row * DM + col] = acc1[mi][ni][r] * g;
      }
    }
}

// ---------------------------------------------------------------------------
extern "C" void kernel_launch(void* const* d_in, const int* in_sizes, int n_in,
                              void* d_out, int out_size, void* d_ws,
                              size_t ws_size, hipStream_t stream) {
  const float* x  = (const float*)d_in[0];
  const float* Wq = (const float*)d_in[1];
  const float* Wk = (const float*)d_in[2];
  const float* Wv = (const float*)d_in[3];
  const float* Wo = (const float*)d_in[4];
  const float* Wg = (const float*)d_in[5];
  float* out = (float*)d_out;

  char* p = (char*)d_ws;
  size_t off = 0;
  auto alloc = [&](size_t bytes) {
    void* r = p + off;
    off = (off + bytes + 255) & ~(size_t)255;
    return r;
  };
  float* Q  = (float*)alloc((size_t)BT * DIM * 4);
  float* Kf = (float*)alloc((size_t)BT * DIM * 4);
  float* Vf = (float*)alloc((size_t)BT * DIM * 4);
  float* Sc = (float*)alloc((size_t)Bb * Hh * NC * Dd * Dd * 4);
  float* zc = (float*)alloc((size_t)Bb * Hh * NC * Dd * 4);
  unsigned short* xb    = (unsigned short*)alloc((size_t)BT * DM * 2);
  unsigned short* WqkvT = (unsigned short*)alloc((size_t)DM * DM * 2);
  unsigned short* WoT   = (unsigned short*)alloc((size_t)DM * DIM * 2);
  unsigned short* WgT   = (unsigned short*)alloc((size_t)DM * DM * 2);
  unsigned short* Ob    = (unsigned short*)alloc((size_t)BT * DIM * 2);

  // 1. casts / transposed weight conversion
  k_cast<<<dim3((BT * DM / 8 + 255) / 256), dim3(256), 0, stream>>>(x, xb, BT * DM / 8);
  dim3 tb(32, 8);
  k_convT<<<dim3(DM / 32, DIM / 32), tb, 0, stream>>>(Wq, WqkvT, DM, DIM, 0,   DM);
  k_convT<<<dim3(DM / 32, DIM / 32), tb, 0, stream>>>(Wk, WqkvT, DM, DIM, 256, DM);
  k_convT<<<dim3(DM / 32, DIM / 32), tb, 0, stream>>>(Wv, WqkvT, DM, DIM, 512, DM);
  k_convT<<<dim3(DIM / 32, DM / 32), tb, 0, stream>>>(Wo, WoT,   DIM, DM, 0,   DIM);
  k_convT<<<dim3(DM / 32, DM / 32),  tb, 0, stream>>>(Wg, WgT,   DM, DM, 0,    DM);

  // 2. QKV projection (MFMA)
  k_gemm_qkv<<<dim3(BT / 128, DM / 128), dim3(256), 0, stream>>>(xb, WqkvT, Q, Kf, Vf);

  // 3. chunked linear attention
  dim3 blk(16, 16);
  k_chunksum<<<dim3(NC, Hh, Bb), blk, 0, stream>>>(Kf, Vf, Sc, zc);
  k_scan<<<dim3(Bb * Hh, Dd * Dd / 256), dim3(256), 0, stream>>>(Sc, zc);
  k_out<<<dim3(NC, Hh, Bb), blk, 0, stream>>>(Q, Kf, Vf, Sc, zc, Ob);

  // 4. fused output GEMM + gate (MFMA)
  k_gemm_final<<<dim3(BT / 128, DM / 128), dim3(256), 0, stream>>>(Ob, WoT, xb, WgT, out);
}